// Round 1
// baseline (563.710 us; speedup 1.0000x reference)
//
#include <hip/hip_runtime.h>
#include <math.h>

#define C_   256
#define B_   16
#define HW_  9216
#define W_   96
#define H_   96
#define P_   16
#define EPS_ 1e-5f

typedef unsigned int u32;

// ---------------------------------------------------------------------------
// K1: k[p][d] = sum_c proto[p][c]*k_w[d][c] + k_b[d];  v likewise.
// grid: 16 blocks (p), 256 threads (d)
// ---------------------------------------------------------------------------
__global__ __launch_bounds__(256) void k_kv(
    const float* __restrict__ proto, const float* __restrict__ kw,
    const float* __restrict__ kb, const float* __restrict__ vw,
    const float* __restrict__ vb, float* __restrict__ wk, float* __restrict__ wv)
{
    __shared__ float pr[C_];
    const int p = blockIdx.x, d = threadIdx.x;
    pr[d] = proto[p * C_ + d];
    __syncthreads();
    float kk = kb[d], vv = vb[d];
    const float* kr = kw + d * C_;
    const float* vr = vw + d * C_;
    #pragma unroll 8
    for (int c = 0; c < C_; ++c) {
        const float pc = pr[c];
        kk = fmaf(pc, kr[c], kk);
        vv = fmaf(pc, vr[c], vv);
    }
    wk[p * C_ + d] = kk;
    wv[p * C_ + d] = vv;
}

// ---------------------------------------------------------------------------
// K2: blocks 0..15:  m[c][p] = sum_d q_w[d][c]*k[p][d];  s0[p] = sum_d q_b[d]*k[p][d]
//     blocks 16..31: u[d][p] = sum_c v[p][c]*out_w[d][c]
// ---------------------------------------------------------------------------
__global__ __launch_bounds__(256) void k_mu(
    const float* __restrict__ wk, const float* __restrict__ wv,
    const float* __restrict__ qw, const float* __restrict__ qb,
    const float* __restrict__ ow,
    float* __restrict__ wm, float* __restrict__ wu, float* __restrict__ ws0)
{
    __shared__ float row[C_];
    __shared__ float red[C_];
    const int blk = blockIdx.x, t = threadIdx.x;
    if (blk < 16) {
        const int p = blk;
        row[t] = wk[p * C_ + t];
        __syncthreads();
        float mm = 0.f;
        #pragma unroll 8
        for (int d = 0; d < C_; ++d)
            mm = fmaf(row[d], qw[d * C_ + t], mm);
        wm[t * P_ + p] = mm;
        red[t] = qb[t] * row[t];
        __syncthreads();
        for (int s = 128; s > 0; s >>= 1) {
            if (t < s) red[t] += red[t + s];
            __syncthreads();
        }
        if (t == 0) ws0[p] = red[0];
    } else {
        const int p = blk - 16;
        row[t] = wv[p * C_ + t];
        __syncthreads();
        float uu = 0.f;
        const float* orow = ow + t * C_;
        #pragma unroll 8
        for (int c = 0; c < C_; ++c)
            uu = fmaf(row[c], orow[c], uu);
        wu[t * P_ + p] = uu;
    }
}

// ---------------------------------------------------------------------------
// K3: pd[p][n] = sum_c bilerp(pos[c])[n] * m[c][p]
// half-pixel centers, clamped edges (== jax.image.resize bilinear upsample)
// grid: 36 blocks, 256 threads (one pixel each)
// ---------------------------------------------------------------------------
__global__ __launch_bounds__(256) void k_pd(
    const float* __restrict__ pos, const float* __restrict__ m,
    float* __restrict__ pd)
{
    const int n = blockIdx.x * 256 + threadIdx.x;
    const int h = n / W_, w = n - h * W_;
    float sy = (h + 0.5f) * (2.0f / 3.0f) - 0.5f;
    float sx = (w + 0.5f) * (2.0f / 3.0f) - 0.5f;
    sy = fminf(fmaxf(sy, 0.f), 63.f);
    sx = fminf(fmaxf(sx, 0.f), 63.f);
    const int y0 = (int)sy, x0 = (int)sx;
    const float fy = sy - (float)y0, fx = sx - (float)x0;
    const int y1 = min(y0 + 1, 63), x1 = min(x0 + 1, 63);
    const float w00 = (1.f - fy) * (1.f - fx), w01 = (1.f - fy) * fx;
    const float w10 = fy * (1.f - fx),         w11 = fy * fx;
    const int i00 = y0 * 64 + x0, i01 = y0 * 64 + x1;
    const int i10 = y1 * 64 + x0, i11 = y1 * 64 + x1;

    float acc[P_];
    #pragma unroll
    for (int p = 0; p < P_; ++p) acc[p] = 0.f;

    #pragma unroll 4
    for (int c = 0; c < C_; ++c) {
        const float* pc = pos + c * 4096;
        const float pv = pc[i00] * w00 + pc[i01] * w01 +
                         pc[i10] * w10 + pc[i11] * w11;
        #pragma unroll
        for (int p = 0; p < P_; ++p)
            acc[p] = fmaf(pv, m[c * P_ + p], acc[p]);
    }
    #pragma unroll
    for (int p = 0; p < P_; ++p) pd[p * HW_ + n] = acc[p];
}

// ---------------------------------------------------------------------------
// K4 (main): per pixel n of image b:
//   logits[p] = (x[b,:,n]·m[:,p] + pd[p,n] + s0[p]) * 1/16 -> softmax ->
//   o2[b,d,n] = sum_p attn[p]*u[d][p] + out_b[d]    (fp32, staged in d_out)
// grid: (36, 16), 256 threads
// c-loop restructured: 8 independent loads batched BEFORE any FMA so the
// wave keeps >=8 global loads in flight (MLP; we are latency-bound at
// ~2.25 waves/SIMD occupancy).
// ---------------------------------------------------------------------------
__global__ __launch_bounds__(256) void k_attn(
    const float* __restrict__ x, const float* __restrict__ m,
    const float* __restrict__ u, const float* __restrict__ s0,
    const float* __restrict__ pd, const float* __restrict__ outb,
    float* __restrict__ o2)
{
    const int b = blockIdx.y;
    const int n = blockIdx.x * 256 + threadIdx.x;
    const float* xp = x + (size_t)b * (C_ * HW_) + n;

    float acc[P_];
    #pragma unroll
    for (int p = 0; p < P_; ++p) acc[p] = 0.f;

    for (int c0 = 0; c0 < C_; c0 += 8) {
        float xv[8];
        #pragma unroll
        for (int j = 0; j < 8; ++j)
            xv[j] = xp[(size_t)(c0 + j) * HW_];
        #pragma unroll
        for (int j = 0; j < 8; ++j) {
            const float* mr = m + (c0 + j) * P_;
            #pragma unroll
            for (int p = 0; p < P_; ++p)
                acc[p] = fmaf(xv[j], mr[p], acc[p]);
        }
    }

    float l[P_];
    float mx = -1e30f;
    #pragma unroll
    for (int p = 0; p < P_; ++p) {
        l[p] = (acc[p] + pd[p * HW_ + n] + s0[p]) * 0.0625f;
        mx = fmaxf(mx, l[p]);
    }
    float sum = 0.f;
    #pragma unroll
    for (int p = 0; p < P_; ++p) { l[p] = __expf(l[p] - mx); sum += l[p]; }
    const float r = 1.f / sum;
    #pragma unroll
    for (int p = 0; p < P_; ++p) l[p] *= r;

    float* op = o2 + (size_t)b * (C_ * HW_) + n;
    #pragma unroll 4
    for (int d = 0; d < C_; ++d) {
        float o = outb[d];
        #pragma unroll
        for (int p = 0; p < P_; ++p)
            o = fmaf(l[p], u[d * P_ + p], o);
        op[(size_t)d * HW_] = o;
    }
}

// ---------------------------------------------------------------------------
// K5: per (b,c) plane: dw3x3(o2) -> BN(eval) -> exact GELU; y = o2+gelu+x.
// o2 is staged in d_out; the FULL plane is loaded to LDS before any write,
// so overwriting the same plane in place is race-free (one block per plane).
// Block-reduced sum/sumsq atomically -> 128 (b,group) cells.
// MLP fixes: halo-only zeroing (one barrier), unroll-4 fill + main loops so
// 4 independent global loads are in flight per wave.
// grid: (256, 16), 256 threads
// ---------------------------------------------------------------------------
__global__ __launch_bounds__(256) void k_local(
    const float* __restrict__ x,
    const float* __restrict__ dww, const float* __restrict__ bng,
    const float* __restrict__ bnb, const float* __restrict__ bnm,
    const float* __restrict__ bnv,
    float* __restrict__ y, float* __restrict__ sums)
{
    __shared__ float tile[98 * 98];
    __shared__ float red[512];
    const int c = blockIdx.x, b = blockIdx.y, t = threadIdx.x;

    // zero only the halo ring (interior is fully overwritten by the fill)
    if (t < 98) { tile[t] = 0.f; tile[97 * 98 + t] = 0.f; }
    if (t < 96) { tile[(t + 1) * 98] = 0.f; tile[(t + 1) * 98 + 97] = 0.f; }

    const size_t plane = (size_t)(b * C_ + c) * HW_;
    const float* op = y + plane;   // o2 staged here by k_attn
    #pragma unroll 4
    for (int k = 0; k < 36; ++k) {
        const int i = t + k * 256;
        const int h = i / W_, w = i - h * W_;
        tile[(h + 1) * 98 + (w + 1)] = op[i];
    }
    __syncthreads();

    const float w00 = dww[c * 9 + 0], w01 = dww[c * 9 + 1], w02 = dww[c * 9 + 2];
    const float w10 = dww[c * 9 + 3], w11 = dww[c * 9 + 4], w12 = dww[c * 9 + 5];
    const float w20 = dww[c * 9 + 6], w21 = dww[c * 9 + 7], w22 = dww[c * 9 + 8];
    const float inv  = bng[c] * rsqrtf(bnv[c] + EPS_);
    const float mu   = bnm[c];
    const float beta = bnb[c];

    const float* xp = x + plane;
    float* yp = y + plane;
    float s1 = 0.f, s2 = 0.f;

    #pragma unroll 4
    for (int k = 0; k < 36; ++k) {
        const int i = t + k * 256;
        const float xv = xp[i];            // hoisted: issue load before conv
        const int h = i / W_, w = i - h * W_;
        const float* ctr = &tile[(h + 1) * 98 + (w + 1)];
        float dwv = ctr[-99] * w00 + ctr[-98] * w01 + ctr[-97] * w02
                  + ctr[-1]  * w10 + ctr[0]   * w11 + ctr[1]   * w12
                  + ctr[97]  * w20 + ctr[98]  * w21 + ctr[99]  * w22;
        const float bn = (dwv - mu) * inv + beta;
        const float g  = 0.5f * bn * (1.f + erff(bn * 0.70710678118654752f));
        const float yv = ctr[0] + g + xv;
        s1 += yv;
        s2 = fmaf(yv, yv, s2);
        yp[i] = yv;
    }

    red[t] = s1; red[256 + t] = s2;
    __syncthreads();
    for (int s = 128; s > 0; s >>= 1) {
        if (t < s) { red[t] += red[t + s]; red[256 + t] += red[256 + t + s]; }
        __syncthreads();
    }
    if (t == 0) {
        const int bg = b * 8 + (c >> 5);
        atomicAdd(&sums[bg * 2 + 0], red[0]);
        atomicAdd(&sums[bg * 2 + 1], red[256]);
    }
}

// ---------------------------------------------------------------------------
// K6: GroupNorm normalize, in place on d_out. 4 elems/thread (one float4).
// grid: 36864 blocks, 256 threads
// ---------------------------------------------------------------------------
__global__ __launch_bounds__(256) void k_norm(
    const float* __restrict__ sums, const float* __restrict__ gng,
    const float* __restrict__ gnb, float* __restrict__ y)
{
    const u32 i0 = ((u32)blockIdx.x * 256u + threadIdx.x) * 4u;
    const u32 plane = i0 / HW_;            // b*256 + c
    const u32 c = plane & 255u;
    const u32 b = plane >> 8;
    const u32 bg = b * 8u + (c >> 5);
    const float cntinv = 1.f / 294912.f;   // 32 ch * 9216 px
    const float mean = sums[bg * 2 + 0] * cntinv;
    const float var  = fmaf(sums[bg * 2 + 1], cntinv, -mean * mean);
    const float inv  = rsqrtf(var + EPS_);
    const float a  = gng[c] * inv;
    const float bb = gnb[c] - mean * a;

    float4 v = *reinterpret_cast<const float4*>(y + i0);
    v.x = fmaf(v.x, a, bb);
    v.y = fmaf(v.y, a, bb);
    v.z = fmaf(v.z, a, bb);
    v.w = fmaf(v.w, a, bb);
    *reinterpret_cast<float4*>(y + i0) = v;
}

// ---------------------------------------------------------------------------
extern "C" void kernel_launch(void* const* d_in, const int* in_sizes, int n_in,
                              void* d_out, int out_size, void* d_ws, size_t ws_size,
                              hipStream_t stream)
{
    const float* x     = (const float*)d_in[0];
    const float* proto = (const float*)d_in[1];
    const float* pos   = (const float*)d_in[2];
    const float* qw    = (const float*)d_in[3];
    const float* qb    = (const float*)d_in[4];
    const float* kw    = (const float*)d_in[5];
    const float* kb    = (const float*)d_in[6];
    const float* vw    = (const float*)d_in[7];
    const float* vb    = (const float*)d_in[8];
    const float* ow    = (const float*)d_in[9];
    const float* ob    = (const float*)d_in[10];
    const float* dww   = (const float*)d_in[11];
    const float* bng   = (const float*)d_in[12];
    const float* bnb   = (const float*)d_in[13];
    const float* bnm   = (const float*)d_in[14];
    const float* bnv   = (const float*)d_in[15];
    const float* gng   = (const float*)d_in[16];
    const float* gnb   = (const float*)d_in[17];

    char* ws = (char*)d_ws;
    float* sums = (float*)(ws);                        // 128*2*4 = 1024 B
    float* s0   = (float*)(ws + 1024);                 // 64 B
    float* wk   = (float*)(ws + 2048);                 // 16 KB
    float* wv   = (float*)(ws + 2048 + 16384);         // 16 KB
    float* wm   = (float*)(ws + 2048 + 2 * 16384);     // 16 KB  [c][p]
    float* wu   = (float*)(ws + 2048 + 3 * 16384);     // 16 KB  [d][p]
    float* pd   = (float*)(ws + 2048 + 4 * 16384);     // 576 KB [p][n]
    // total ws usage: < 1 MB

    float* out = (float*)d_out;

    hipMemsetAsync(sums, 0, 1024, stream);
    k_kv<<<16, 256, 0, stream>>>(proto, kw, kb, vw, vb, wk, wv);
    k_mu<<<32, 256, 0, stream>>>(wk, wv, qw, qb, ow, wm, wu, s0);
    k_pd<<<36, 256, 0, stream>>>(pos, wm, pd);
    k_attn<<<dim3(36, 16), 256, 0, stream>>>(x, wm, wu, s0, pd, ob, out);
    k_local<<<dim3(256, 16), 256, 0, stream>>>(x, dww, bng, bnb, bnm, bnv, out, sums);
    k_norm<<<36864, 256, 0, stream>>>(sums, gng, gnb, out);
}

// Round 2
// 533.437 us; speedup vs baseline: 1.0568x; 1.0568x over previous
//
#include <hip/hip_runtime.h>
#include <math.h>

#define C_   256
#define B_   16
#define HW_  9216
#define W_   96
#define H_   96
#define P_   16
#define EPS_ 1e-5f

typedef unsigned int u32;

// ---------------------------------------------------------------------------
// K1: k[p][d] = sum_c proto[p][c]*k_w[d][c] + k_b[d];  v likewise.
// Block 0 also zeroes the 256-float GroupNorm sums buffer (replaces memset).
// grid: 16 blocks (p), 256 threads (d)
// ---------------------------------------------------------------------------
__global__ __launch_bounds__(256) void k_kv(
    const float* __restrict__ proto, const float* __restrict__ kw,
    const float* __restrict__ kb, const float* __restrict__ vw,
    const float* __restrict__ vb, float* __restrict__ wk, float* __restrict__ wv,
    float* __restrict__ sums)
{
    __shared__ float pr[C_];
    const int p = blockIdx.x, d = threadIdx.x;
    if (p == 0) sums[d] = 0.f;   // 128*2 floats == 256 == blockDim
    pr[d] = proto[p * C_ + d];
    __syncthreads();
    float kk = kb[d], vv = vb[d];
    const float* kr = kw + d * C_;
    const float* vr = vw + d * C_;
    #pragma unroll 8
    for (int c = 0; c < C_; ++c) {
        const float pc = pr[c];
        kk = fmaf(pc, kr[c], kk);
        vv = fmaf(pc, vr[c], vv);
    }
    wk[p * C_ + d] = kk;
    wv[p * C_ + d] = vv;
}

// ---------------------------------------------------------------------------
// K2: blocks 0..15:  m[c][p] = sum_d q_w[d][c]*k[p][d];  s0[p] = sum_d q_b[d]*k[p][d]
//     blocks 16..31: u[d][p] = sum_c v[p][c]*out_w[d][c]
// ---------------------------------------------------------------------------
__global__ __launch_bounds__(256) void k_mu(
    const float* __restrict__ wk, const float* __restrict__ wv,
    const float* __restrict__ qw, const float* __restrict__ qb,
    const float* __restrict__ ow,
    float* __restrict__ wm, float* __restrict__ wu, float* __restrict__ ws0)
{
    __shared__ float row[C_];
    __shared__ float red[C_];
    const int blk = blockIdx.x, t = threadIdx.x;
    if (blk < 16) {
        const int p = blk;
        row[t] = wk[p * C_ + t];
        __syncthreads();
        float mm = 0.f;
        #pragma unroll 8
        for (int d = 0; d < C_; ++d)
            mm = fmaf(row[d], qw[d * C_ + t], mm);
        wm[t * P_ + p] = mm;
        red[t] = qb[t] * row[t];
        __syncthreads();
        for (int s = 128; s > 0; s >>= 1) {
            if (t < s) red[t] += red[t + s];
            __syncthreads();
        }
        if (t == 0) ws0[p] = red[0];
    } else {
        const int p = blk - 16;
        row[t] = wv[p * C_ + t];
        __syncthreads();
        float uu = 0.f;
        const float* orow = ow + t * C_;
        #pragma unroll 8
        for (int c = 0; c < C_; ++c)
            uu = fmaf(row[c], orow[c], uu);
        wu[t * P_ + p] = uu;
    }
}

// ---------------------------------------------------------------------------
// K3: pd[p][n] = sum_c bilerp(pos[c])[n] * m[c][p]
// half-pixel centers, clamped edges (== jax.image.resize bilinear upsample)
// grid: 36 blocks, 256 threads (one pixel each)
// ---------------------------------------------------------------------------
__global__ __launch_bounds__(256) void k_pd(
    const float* __restrict__ pos, const float* __restrict__ m,
    float* __restrict__ pd)
{
    const int n = blockIdx.x * 256 + threadIdx.x;
    const int h = n / W_, w = n - h * W_;
    float sy = (h + 0.5f) * (2.0f / 3.0f) - 0.5f;
    float sx = (w + 0.5f) * (2.0f / 3.0f) - 0.5f;
    sy = fminf(fmaxf(sy, 0.f), 63.f);
    sx = fminf(fmaxf(sx, 0.f), 63.f);
    const int y0 = (int)sy, x0 = (int)sx;
    const float fy = sy - (float)y0, fx = sx - (float)x0;
    const int y1 = min(y0 + 1, 63), x1 = min(x0 + 1, 63);
    const float w00 = (1.f - fy) * (1.f - fx), w01 = (1.f - fy) * fx;
    const float w10 = fy * (1.f - fx),         w11 = fy * fx;
    const int i00 = y0 * 64 + x0, i01 = y0 * 64 + x1;
    const int i10 = y1 * 64 + x0, i11 = y1 * 64 + x1;

    float acc[P_];
    #pragma unroll
    for (int p = 0; p < P_; ++p) acc[p] = 0.f;

    #pragma unroll 4
    for (int c = 0; c < C_; ++c) {
        const float* pc = pos + c * 4096;
        const float pv = pc[i00] * w00 + pc[i01] * w01 +
                         pc[i10] * w10 + pc[i11] * w11;
        #pragma unroll
        for (int p = 0; p < P_; ++p)
            acc[p] = fmaf(pv, m[c * P_ + p], acc[p]);
    }
    #pragma unroll
    for (int p = 0; p < P_; ++p) pd[p * HW_ + n] = acc[p];
}

// ---------------------------------------------------------------------------
// K4 (main): 2 pixels per thread (float2 IO).
//   logits[p] = (x[b,:,n]·m[:,p] + pd[p,n] + s0[p]) * 1/16 -> softmax ->
//   o2[b,d,n] = sum_p attn[p]*u[d][p] + out_b[d]    (fp32, staged in d_out)
// c-loop batches 8 float2 loads before any FMA (MLP: ~36 KB/CU in flight);
// the 256-d output loop amortizes u-row broadcast + store over 2 px.
// grid: (18, 16), 256 threads
// ---------------------------------------------------------------------------
__global__ __launch_bounds__(256) void k_attn(
    const float* __restrict__ x, const float* __restrict__ m,
    const float* __restrict__ u, const float* __restrict__ s0,
    const float* __restrict__ pd, const float* __restrict__ outb,
    float* __restrict__ o2)
{
    const int b = blockIdx.y;
    const int n0 = (blockIdx.x * 256 + threadIdx.x) * 2;
    const float* xp = x + (size_t)b * (C_ * HW_) + n0;

    float acc0[P_], acc1[P_];
    #pragma unroll
    for (int p = 0; p < P_; ++p) { acc0[p] = 0.f; acc1[p] = 0.f; }

    for (int cc = 0; cc < C_; cc += 8) {
        float2 xv[8];
        #pragma unroll
        for (int j = 0; j < 8; ++j)
            xv[j] = *reinterpret_cast<const float2*>(xp + (size_t)(cc + j) * HW_);
        #pragma unroll
        for (int j = 0; j < 8; ++j) {
            const float* mr = m + (cc + j) * P_;
            #pragma unroll
            for (int p = 0; p < P_; ++p) {
                acc0[p] = fmaf(xv[j].x, mr[p], acc0[p]);
                acc1[p] = fmaf(xv[j].y, mr[p], acc1[p]);
            }
        }
    }

    float l0[P_], l1[P_];
    float mx0 = -1e30f, mx1 = -1e30f;
    #pragma unroll
    for (int p = 0; p < P_; ++p) {
        const float2 pv = *reinterpret_cast<const float2*>(pd + (size_t)p * HW_ + n0);
        l0[p] = (acc0[p] + pv.x + s0[p]) * 0.0625f;
        l1[p] = (acc1[p] + pv.y + s0[p]) * 0.0625f;
        mx0 = fmaxf(mx0, l0[p]);
        mx1 = fmaxf(mx1, l1[p]);
    }
    float sum0 = 0.f, sum1 = 0.f;
    #pragma unroll
    for (int p = 0; p < P_; ++p) {
        l0[p] = __expf(l0[p] - mx0); sum0 += l0[p];
        l1[p] = __expf(l1[p] - mx1); sum1 += l1[p];
    }
    const float r0 = 1.f / sum0, r1 = 1.f / sum1;
    #pragma unroll
    for (int p = 0; p < P_; ++p) { l0[p] *= r0; l1[p] *= r1; }

    float* op = o2 + (size_t)b * (C_ * HW_) + n0;
    #pragma unroll 4
    for (int d = 0; d < C_; ++d) {
        const float* ur = u + d * P_;
        float o0 = outb[d], o1 = o0;
        #pragma unroll
        for (int p = 0; p < P_; ++p) {
            o0 = fmaf(l0[p], ur[p], o0);
            o1 = fmaf(l1[p], ur[p], o1);
        }
        *reinterpret_cast<float2*>(op + (size_t)d * HW_) = make_float2(o0, o1);
    }
}

// ---------------------------------------------------------------------------
// K5: per (b,c) plane: dw3x3(o2) -> BN(eval) -> exact GELU; y = o2+gelu+x.
// o2 is staged in d_out; the FULL plane is loaded to LDS before any write,
// so overwriting the same plane in place is race-free (one block per plane).
// v2: 4-px micro-tile per thread. Tile stride 100 (16B-aligned rows, interior
// at col 2) so each stencil row is two ds_read_b128 -> 1.5 LDS instr/px
// (was 9 ds_read_b32/px). Reduction buffer aliases the tile (LDS stays
// 39.2 KB -> 4 blocks/CU). All global IO is float4.
// grid: (256, 16), 256 threads
// ---------------------------------------------------------------------------
__global__ __launch_bounds__(256) void k_local(
    const float* __restrict__ x,
    const float* __restrict__ dww, const float* __restrict__ bng,
    const float* __restrict__ bnb, const float* __restrict__ bnm,
    const float* __restrict__ bnv,
    float* __restrict__ y, float* __restrict__ sums)
{
    __shared__ float tile[98 * 100];   // row r=h+1, col = w+2; cols 0,99 pad
    const int c = blockIdx.x, b = blockIdx.y, t = threadIdx.x;

    // zero halo ring (interior fully overwritten by the fill)
    if (t < 100) { tile[t] = 0.f; tile[97 * 100 + t] = 0.f; }
    if (t < 96)  { tile[(t + 1) * 100 + 1] = 0.f; tile[(t + 1) * 100 + 98] = 0.f; }

    const size_t plane = (size_t)(b * C_ + c) * HW_;
    const float4* op4 = reinterpret_cast<const float4*>(y + plane);  // o2 staged here
    #pragma unroll
    for (int k = 0; k < 9; ++k) {
        const int g = t + k * 256;           // group of 4 px; 24 groups/row
        const int h = g / 24;
        const int w0 = (g - h * 24) * 4;
        const float4 v = op4[g];
        const int base = (h + 1) * 100 + w0 + 2;   // 8B-aligned
        *reinterpret_cast<float2*>(&tile[base])     = make_float2(v.x, v.y);
        *reinterpret_cast<float2*>(&tile[base + 2]) = make_float2(v.z, v.w);
    }
    __syncthreads();

    const float w00 = dww[c * 9 + 0], w01 = dww[c * 9 + 1], w02 = dww[c * 9 + 2];
    const float w10 = dww[c * 9 + 3], w11 = dww[c * 9 + 4], w12 = dww[c * 9 + 5];
    const float w20 = dww[c * 9 + 6], w21 = dww[c * 9 + 7], w22 = dww[c * 9 + 8];
    const float inv  = bng[c] * rsqrtf(bnv[c] + EPS_);
    const float mu   = bnm[c];
    const float beta = bnb[c];

    const float4* xp4 = reinterpret_cast<const float4*>(x + plane);
    float4* yp4 = reinterpret_cast<float4*>(y + plane);
    float s1 = 0.f, s2 = 0.f;

    #pragma unroll
    for (int k = 0; k < 9; ++k) {
        const int g = t + k * 256;
        const float4 xv = xp4[g];            // issue global load first
        const int h = g / 24;
        const int w0 = (g - h * 24) * 4;
        const int r0 = h * 100 + w0;         // tile row h == image row h-1
        const float4 a0 = *reinterpret_cast<const float4*>(&tile[r0]);
        const float4 a1 = *reinterpret_cast<const float4*>(&tile[r0 + 4]);
        const float4 b0 = *reinterpret_cast<const float4*>(&tile[r0 + 100]);
        const float4 b1 = *reinterpret_cast<const float4*>(&tile[r0 + 104]);
        const float4 c0 = *reinterpret_cast<const float4*>(&tile[r0 + 200]);
        const float4 c1 = *reinterpret_cast<const float4*>(&tile[r0 + 204]);
        const float A[8]  = {a0.x, a0.y, a0.z, a0.w, a1.x, a1.y, a1.z, a1.w};
        const float Bv[8] = {b0.x, b0.y, b0.z, b0.w, b1.x, b1.y, b1.z, b1.w};
        const float Cv[8] = {c0.x, c0.y, c0.z, c0.w, c1.x, c1.y, c1.z, c1.w};
        const float xs[4] = {xv.x, xv.y, xv.z, xv.w};
        float ys[4];
        #pragma unroll
        for (int j = 0; j < 4; ++j) {        // fully unrolled -> static indices
            float dwv = A[j + 1] * w00 + A[j + 2] * w01 + A[j + 3] * w02
                      + Bv[j + 1] * w10 + Bv[j + 2] * w11 + Bv[j + 3] * w12
                      + Cv[j + 1] * w20 + Cv[j + 2] * w21 + Cv[j + 3] * w22;
            const float bn = (dwv - mu) * inv + beta;
            const float gl = 0.5f * bn * (1.f + erff(bn * 0.70710678118654752f));
            const float yv = Bv[j + 2] + gl + xs[j];
            s1 += yv;
            s2 = fmaf(yv, yv, s2);
            ys[j] = yv;
        }
        yp4[g] = make_float4(ys[0], ys[1], ys[2], ys[3]);
    }

    __syncthreads();                 // all tile reads done -> safe to alias
    float* red = tile;               // reuse LDS for the block reduction
    red[t] = s1; red[256 + t] = s2;
    __syncthreads();
    for (int s = 128; s > 0; s >>= 1) {
        if (t < s) { red[t] += red[t + s]; red[256 + t] += red[256 + t + s]; }
        __syncthreads();
    }
    if (t == 0) {
        const int bg = b * 8 + (c >> 5);
        atomicAdd(&sums[bg * 2 + 0], red[0]);
        atomicAdd(&sums[bg * 2 + 1], red[256]);
    }
}

// ---------------------------------------------------------------------------
// K6: GroupNorm normalize, in place on d_out. 4 elems/thread (one float4).
// grid: 36864 blocks, 256 threads
// ---------------------------------------------------------------------------
__global__ __launch_bounds__(256) void k_norm(
    const float* __restrict__ sums, const float* __restrict__ gng,
    const float* __restrict__ gnb, float* __restrict__ y)
{
    const u32 i0 = ((u32)blockIdx.x * 256u + threadIdx.x) * 4u;
    const u32 plane = i0 / HW_;            // b*256 + c
    const u32 c = plane & 255u;
    const u32 b = plane >> 8;
    const u32 bg = b * 8u + (c >> 5);
    const float cntinv = 1.f / 294912.f;   // 32 ch * 9216 px
    const float mean = sums[bg * 2 + 0] * cntinv;
    const float var  = fmaf(sums[bg * 2 + 1], cntinv, -mean * mean);
    const float inv  = rsqrtf(var + EPS_);
    const float a  = gng[c] * inv;
    const float bb = gnb[c] - mean * a;

    float4 v = *reinterpret_cast<const float4*>(y + i0);
    v.x = fmaf(v.x, a, bb);
    v.y = fmaf(v.y, a, bb);
    v.z = fmaf(v.z, a, bb);
    v.w = fmaf(v.w, a, bb);
    *reinterpret_cast<float4*>(y + i0) = v;
}

// ---------------------------------------------------------------------------
extern "C" void kernel_launch(void* const* d_in, const int* in_sizes, int n_in,
                              void* d_out, int out_size, void* d_ws, size_t ws_size,
                              hipStream_t stream)
{
    const float* x     = (const float*)d_in[0];
    const float* proto = (const float*)d_in[1];
    const float* pos   = (const float*)d_in[2];
    const float* qw    = (const float*)d_in[3];
    const float* qb    = (const float*)d_in[4];
    const float* kw    = (const float*)d_in[5];
    const float* kb    = (const float*)d_in[6];
    const float* vw    = (const float*)d_in[7];
    const float* vb    = (const float*)d_in[8];
    const float* ow    = (const float*)d_in[9];
    const float* ob    = (const float*)d_in[10];
    const float* dww   = (const float*)d_in[11];
    const float* bng   = (const float*)d_in[12];
    const float* bnb   = (const float*)d_in[13];
    const float* bnm   = (const float*)d_in[14];
    const float* bnv   = (const float*)d_in[15];
    const float* gng   = (const float*)d_in[16];
    const float* gnb   = (const float*)d_in[17];

    char* ws = (char*)d_ws;
    float* sums = (float*)(ws);                        // 128*2*4 = 1024 B
    float* s0   = (float*)(ws + 1024);                 // 64 B
    float* wk   = (float*)(ws + 2048);                 // 16 KB
    float* wv   = (float*)(ws + 2048 + 16384);         // 16 KB
    float* wm   = (float*)(ws + 2048 + 2 * 16384);     // 16 KB  [c][p]
    float* wu   = (float*)(ws + 2048 + 3 * 16384);     // 16 KB  [d][p]
    float* pd   = (float*)(ws + 2048 + 4 * 16384);     // 576 KB [p][n]
    // total ws usage: < 1 MB

    float* out = (float*)d_out;

    k_kv<<<16, 256, 0, stream>>>(proto, kw, kb, vw, vb, wk, wv, sums);
    k_mu<<<32, 256, 0, stream>>>(wk, wv, qw, qb, ow, wm, wu, s0);
    k_pd<<<36, 256, 0, stream>>>(pos, wm, pd);
    k_attn<<<dim3(18, 16), 256, 0, stream>>>(x, wm, wu, s0, pd, ob, out);
    k_local<<<dim3(256, 16), 256, 0, stream>>>(x, dww, bng, bnb, bnm, bnv, out, sums);
    k_norm<<<36864, 256, 0, stream>>>(sums, gng, gnb, out);
}

// Round 4
// 528.619 us; speedup vs baseline: 1.0664x; 1.0091x over previous
//
#include <hip/hip_runtime.h>
#include <math.h>

#define C_   256
#define B_   16
#define HW_  9216
#define W_   96
#define H_   96
#define P_   16
#define EPS_ 1e-5f

typedef unsigned int u32;

// ---------------------------------------------------------------------------
// K1: k[p][d] = sum_c proto[p][c]*k_w[d][c] + k_b[d];  v likewise.
// Block 0 also zeroes the 256-float GroupNorm sums buffer (replaces memset).
// grid: 16 blocks (p), 256 threads (d)
// ---------------------------------------------------------------------------
__global__ __launch_bounds__(256) void k_kv(
    const float* __restrict__ proto, const float* __restrict__ kw,
    const float* __restrict__ kb, const float* __restrict__ vw,
    const float* __restrict__ vb, float* __restrict__ wk, float* __restrict__ wv,
    float* __restrict__ sums)
{
    __shared__ float pr[C_];
    const int p = blockIdx.x, d = threadIdx.x;
    if (p == 0) sums[d] = 0.f;   // 128*2 floats == 256 == blockDim
    pr[d] = proto[p * C_ + d];
    __syncthreads();
    float kk = kb[d], vv = vb[d];
    const float* kr = kw + d * C_;
    const float* vr = vw + d * C_;
    #pragma unroll 8
    for (int c = 0; c < C_; ++c) {
        const float pc = pr[c];
        kk = fmaf(pc, kr[c], kk);
        vv = fmaf(pc, vr[c], vv);
    }
    wk[p * C_ + d] = kk;
    wv[p * C_ + d] = vv;
}

// ---------------------------------------------------------------------------
// K2: blocks 0..15:  m[c][p] = sum_d q_w[d][c]*k[p][d];  s0[p] = sum_d q_b[d]*k[p][d]
//     blocks 16..31: u[d][p] = sum_c v[p][c]*out_w[d][c]
// ---------------------------------------------------------------------------
__global__ __launch_bounds__(256) void k_mu(
    const float* __restrict__ wk, const float* __restrict__ wv,
    const float* __restrict__ qw, const float* __restrict__ qb,
    const float* __restrict__ ow,
    float* __restrict__ wm, float* __restrict__ wu, float* __restrict__ ws0)
{
    __shared__ float row[C_];
    __shared__ float red[C_];
    const int blk = blockIdx.x, t = threadIdx.x;
    if (blk < 16) {
        const int p = blk;
        row[t] = wk[p * C_ + t];
        __syncthreads();
        float mm = 0.f;
        #pragma unroll 8
        for (int d = 0; d < C_; ++d)
            mm = fmaf(row[d], qw[d * C_ + t], mm);
        wm[t * P_ + p] = mm;
        red[t] = qb[t] * row[t];
        __syncthreads();
        for (int s = 128; s > 0; s >>= 1) {
            if (t < s) red[t] += red[t + s];
            __syncthreads();
        }
        if (t == 0) ws0[p] = red[0];
    } else {
        const int p = blk - 16;
        row[t] = wv[p * C_ + t];
        __syncthreads();
        float uu = 0.f;
        const float* orow = ow + t * C_;
        #pragma unroll 8
        for (int c = 0; c < C_; ++c)
            uu = fmaf(row[c], orow[c], uu);
        wu[t * P_ + p] = uu;
    }
}

// ---------------------------------------------------------------------------
// K3: pd[p][n] = sum_c bilerp(pos[c])[n] * m[c][p]
// half-pixel centers, clamped edges (== jax.image.resize bilinear upsample)
// grid: 36 blocks, 256 threads (one pixel each)
// ---------------------------------------------------------------------------
__global__ __launch_bounds__(256) void k_pd(
    const float* __restrict__ pos, const float* __restrict__ m,
    float* __restrict__ pd)
{
    const int n = blockIdx.x * 256 + threadIdx.x;
    const int h = n / W_, w = n - h * W_;
    float sy = (h + 0.5f) * (2.0f / 3.0f) - 0.5f;
    float sx = (w + 0.5f) * (2.0f / 3.0f) - 0.5f;
    sy = fminf(fmaxf(sy, 0.f), 63.f);
    sx = fminf(fmaxf(sx, 0.f), 63.f);
    const int y0 = (int)sy, x0 = (int)sx;
    const float fy = sy - (float)y0, fx = sx - (float)x0;
    const int y1 = min(y0 + 1, 63), x1 = min(x0 + 1, 63);
    const float w00 = (1.f - fy) * (1.f - fx), w01 = (1.f - fy) * fx;
    const float w10 = fy * (1.f - fx),         w11 = fy * fx;
    const int i00 = y0 * 64 + x0, i01 = y0 * 64 + x1;
    const int i10 = y1 * 64 + x0, i11 = y1 * 64 + x1;

    float acc[P_];
    #pragma unroll
    for (int p = 0; p < P_; ++p) acc[p] = 0.f;

    #pragma unroll 4
    for (int c = 0; c < C_; ++c) {
        const float* pc = pos + c * 4096;
        const float pv = pc[i00] * w00 + pc[i01] * w01 +
                         pc[i10] * w10 + pc[i11] * w11;
        #pragma unroll
        for (int p = 0; p < P_; ++p)
            acc[p] = fmaf(pv, m[c * P_ + p], acc[p]);
    }
    #pragma unroll
    for (int p = 0; p < P_; ++p) pd[p * HW_ + n] = acc[p];
}

// ---------------------------------------------------------------------------
// K4a: logits + softmax only; writes the 16 attention weights per pixel to
// lw[b][p][HW] (9.4 MB). 1 px/thread, 64-thread blocks -> 2304 blocks = 9
// waves/CU exactly (perfect balance; round-2 k_attn was 1.125 blocks/CU,
// 12% occupancy, 2.0 TB/s). 16-deep load batch -> ~36 KB/CU in flight.
// grid: 2304 blocks, 64 threads
// ---------------------------------------------------------------------------
__global__ __launch_bounds__(64) void k_logits(
    const float* __restrict__ x, const float* __restrict__ m,
    const float* __restrict__ s0, const float* __restrict__ pd,
    float* __restrict__ lw)
{
    const int n = blockIdx.x * 64 + threadIdx.x;   // 0..147455; HW%64==0 so
    const int b = n / HW_;                          // b is block-uniform
    const int npx = n - b * HW_;
    const float* xp = x + (size_t)b * (C_ * HW_) + npx;

    float acc[P_];
    #pragma unroll
    for (int p = 0; p < P_; ++p) acc[p] = 0.f;

    for (int cc = 0; cc < C_; cc += 16) {
        float xv[16];
        #pragma unroll
        for (int j = 0; j < 16; ++j)
            xv[j] = xp[(size_t)(cc + j) * HW_];
        #pragma unroll
        for (int j = 0; j < 16; ++j) {
            const float* mr = m + (cc + j) * P_;
            #pragma unroll
            for (int p = 0; p < P_; ++p)
                acc[p] = fmaf(xv[j], mr[p], acc[p]);
        }
    }

    float l[P_];
    float mx = -1e30f;
    #pragma unroll
    for (int p = 0; p < P_; ++p) {
        l[p] = (acc[p] + pd[(size_t)p * HW_ + npx] + s0[p]) * 0.0625f;
        mx = fmaxf(mx, l[p]);
    }
    float sum = 0.f;
    #pragma unroll
    for (int p = 0; p < P_; ++p) { l[p] = __expf(l[p] - mx); sum += l[p]; }
    const float r = 1.f / sum;

    float* lp = lw + (size_t)b * (P_ * HW_) + npx;
    #pragma unroll
    for (int p = 0; p < P_; ++p) lp[(size_t)p * HW_] = l[p] * r;
}

// ---------------------------------------------------------------------------
// K4b: o2[b,d,n] = ob[d] + sum_p lw[b,p,n]*u[d][p].  Each thread: 4 px
// (float4) x 8 d -> l-loads amortized 8x, u rows block-uniform (s_load).
// Same FMA order as the old fused kernel -> bitwise-identical o2.
// grid: (9, 32, 16), 256 threads
// ---------------------------------------------------------------------------
__global__ __launch_bounds__(256) void k_out(
    const float* __restrict__ lw, const float* __restrict__ u,
    const float* __restrict__ ob, float* __restrict__ o2)
{
    const int b = blockIdx.z;
    const int d0 = blockIdx.y * 8;
    const int px = blockIdx.x * 1024 + threadIdx.x * 4;

    const float* lp = lw + (size_t)b * (P_ * HW_) + px;
    float4 lv[P_];
    #pragma unroll
    for (int p = 0; p < P_; ++p)
        lv[p] = *reinterpret_cast<const float4*>(lp + (size_t)p * HW_);

    float* op = o2 + ((size_t)b * C_ + d0) * HW_ + px;
    #pragma unroll
    for (int j = 0; j < 8; ++j) {
        const int d = d0 + j;
        const float* ur = u + d * P_;
        const float obd = ob[d];
        float4 o = make_float4(obd, obd, obd, obd);
        #pragma unroll
        for (int p = 0; p < P_; ++p) {
            o.x = fmaf(lv[p].x, ur[p], o.x);
            o.y = fmaf(lv[p].y, ur[p], o.y);
            o.z = fmaf(lv[p].z, ur[p], o.z);
            o.w = fmaf(lv[p].w, ur[p], o.w);
        }
        *reinterpret_cast<float4*>(op + (size_t)j * HW_) = o;
    }
}

// ---------------------------------------------------------------------------
// K5: per (b,c) plane: dw3x3(o2) -> BN(eval) -> exact GELU; y = o2+gelu+x.
// o2 is staged in d_out; the FULL plane is loaded to LDS before any write,
// so overwriting the same plane in place is race-free (one block per plane).
// 4-px micro-tile per thread; tile stride 100 (16B-aligned rows, interior at
// col 2) so each stencil row is two ds_read_b128. Reduction aliases the tile.
// grid: (256, 16), 256 threads
// ---------------------------------------------------------------------------
__global__ __launch_bounds__(256) void k_local(
    const float* __restrict__ x,
    const float* __restrict__ dww, const float* __restrict__ bng,
    const float* __restrict__ bnb, const float* __restrict__ bnm,
    const float* __restrict__ bnv,
    float* __restrict__ y, float* __restrict__ sums)
{
    __shared__ float tile[98 * 100];   // row r=h+1, col = w+2; cols 0,99 pad
    const int c = blockIdx.x, b = blockIdx.y, t = threadIdx.x;

    // zero halo ring (interior fully overwritten by the fill)
    if (t < 100) { tile[t] = 0.f; tile[97 * 100 + t] = 0.f; }
    if (t < 96)  { tile[(t + 1) * 100 + 1] = 0.f; tile[(t + 1) * 100 + 98] = 0.f; }

    const size_t plane = (size_t)(b * C_ + c) * HW_;
    const float4* op4 = reinterpret_cast<const float4*>(y + plane);  // o2 staged here
    #pragma unroll
    for (int k = 0; k < 9; ++k) {
        const int g = t + k * 256;           // group of 4 px; 24 groups/row
        const int h = g / 24;
        const int w0 = (g - h * 24) * 4;
        const float4 v = op4[g];
        const int base = (h + 1) * 100 + w0 + 2;   // 8B-aligned
        *reinterpret_cast<float2*>(&tile[base])     = make_float2(v.x, v.y);
        *reinterpret_cast<float2*>(&tile[base + 2]) = make_float2(v.z, v.w);
    }
    __syncthreads();

    const float w00 = dww[c * 9 + 0], w01 = dww[c * 9 + 1], w02 = dww[c * 9 + 2];
    const float w10 = dww[c * 9 + 3], w11 = dww[c * 9 + 4], w12 = dww[c * 9 + 5];
    const float w20 = dww[c * 9 + 6], w21 = dww[c * 9 + 7], w22 = dww[c * 9 + 8];
    const float inv  = bng[c] * rsqrtf(bnv[c] + EPS_);
    const float mu   = bnm[c];
    const float beta = bnb[c];

    const float4* xp4 = reinterpret_cast<const float4*>(x + plane);
    float4* yp4 = reinterpret_cast<float4*>(y + plane);
    float s1 = 0.f, s2 = 0.f;

    #pragma unroll
    for (int k = 0; k < 9; ++k) {
        const int g = t + k * 256;
        const float4 xv = xp4[g];            // issue global load first
        const int h = g / 24;
        const int w0 = (g - h * 24) * 4;
        const int r0 = h * 100 + w0;         // tile row h == image row h-1
        const float4 a0 = *reinterpret_cast<const float4*>(&tile[r0]);
        const float4 a1 = *reinterpret_cast<const float4*>(&tile[r0 + 4]);
        const float4 b0 = *reinterpret_cast<const float4*>(&tile[r0 + 100]);
        const float4 b1 = *reinterpret_cast<const float4*>(&tile[r0 + 104]);
        const float4 c0 = *reinterpret_cast<const float4*>(&tile[r0 + 200]);
        const float4 c1 = *reinterpret_cast<const float4*>(&tile[r0 + 204]);
        const float A[8]  = {a0.x, a0.y, a0.z, a0.w, a1.x, a1.y, a1.z, a1.w};
        const float Bv[8] = {b0.x, b0.y, b0.z, b0.w, b1.x, b1.y, b1.z, b1.w};
        const float Cv[8] = {c0.x, c0.y, c0.z, c0.w, c1.x, c1.y, c1.z, c1.w};
        const float xs[4] = {xv.x, xv.y, xv.z, xv.w};
        float ys[4];
        #pragma unroll
        for (int j = 0; j < 4; ++j) {        // fully unrolled -> static indices
            float dwv = A[j + 1] * w00 + A[j + 2] * w01 + A[j + 3] * w02
                      + Bv[j + 1] * w10 + Bv[j + 2] * w11 + Bv[j + 3] * w12
                      + Cv[j + 1] * w20 + Cv[j + 2] * w21 + Cv[j + 3] * w22;
            const float bn = (dwv - mu) * inv + beta;
            const float gl = 0.5f * bn * (1.f + erff(bn * 0.70710678118654752f));
            const float yv = Bv[j + 2] + gl + xs[j];
            s1 += yv;
            s2 = fmaf(yv, yv, s2);
            ys[j] = yv;
        }
        yp4[g] = make_float4(ys[0], ys[1], ys[2], ys[3]);
    }

    __syncthreads();                 // all tile reads done -> safe to alias
    float* red = tile;               // reuse LDS for the block reduction
    red[t] = s1; red[256 + t] = s2;
    __syncthreads();
    for (int s = 128; s > 0; s >>= 1) {
        if (t < s) { red[t] += red[t + s]; red[256 + t] += red[256 + t + s]; }
        __syncthreads();
    }
    if (t == 0) {
        const int bg = b * 8 + (c >> 5);
        atomicAdd(&sums[bg * 2 + 0], red[0]);
        atomicAdd(&sums[bg * 2 + 1], red[256]);
    }
}

// ---------------------------------------------------------------------------
// K6: GroupNorm normalize, in place on d_out. 4 elems/thread (one float4).
// grid: 36864 blocks, 256 threads
// ---------------------------------------------------------------------------
__global__ __launch_bounds__(256) void k_norm(
    const float* __restrict__ sums, const float* __restrict__ gng,
    const float* __restrict__ gnb, float* __restrict__ y)
{
    const u32 i0 = ((u32)blockIdx.x * 256u + threadIdx.x) * 4u;
    const u32 plane = i0 / HW_;            // b*256 + c
    const u32 c = plane & 255u;
    const u32 b = plane >> 8;
    const u32 bg = b * 8u + (c >> 5);
    const float cntinv = 1.f / 294912.f;   // 32 ch * 9216 px
    const float mean = sums[bg * 2 + 0] * cntinv;
    const float var  = fmaf(sums[bg * 2 + 1], cntinv, -mean * mean);
    const float inv  = rsqrtf(var + EPS_);
    const float a  = gng[c] * inv;
    const float bb = gnb[c] - mean * a;

    float4 v = *reinterpret_cast<const float4*>(y + i0);
    v.x = fmaf(v.x, a, bb);
    v.y = fmaf(v.y, a, bb);
    v.z = fmaf(v.z, a, bb);
    v.w = fmaf(v.w, a, bb);
    *reinterpret_cast<float4*>(y + i0) = v;
}

// ---------------------------------------------------------------------------
extern "C" void kernel_launch(void* const* d_in, const int* in_sizes, int n_in,
                              void* d_out, int out_size, void* d_ws, size_t ws_size,
                              hipStream_t stream)
{
    const float* x     = (const float*)d_in[0];
    const float* proto = (const float*)d_in[1];
    const float* pos   = (const float*)d_in[2];
    const float* qw    = (const float*)d_in[3];
    const float* qb    = (const float*)d_in[4];
    const float* kw    = (const float*)d_in[5];
    const float* kb    = (const float*)d_in[6];
    const float* vw    = (const float*)d_in[7];
    const float* vb    = (const float*)d_in[8];
    const float* ow    = (const float*)d_in[9];
    const float* ob    = (const float*)d_in[10];
    const float* dww   = (const float*)d_in[11];
    const float* bng   = (const float*)d_in[12];
    const float* bnb   = (const float*)d_in[13];
    const float* bnm   = (const float*)d_in[14];
    const float* bnv   = (const float*)d_in[15];
    const float* gng   = (const float*)d_in[16];
    const float* gnb   = (const float*)d_in[17];

    char* ws = (char*)d_ws;
    float* sums = (float*)(ws);                        // 128*2*4 = 1024 B
    float* s0   = (float*)(ws + 1024);                 // 64 B
    float* wk   = (float*)(ws + 2048);                 // 16 KB
    float* wv   = (float*)(ws + 2048 + 16384);         // 16 KB
    float* wm   = (float*)(ws + 2048 + 2 * 16384);     // 16 KB  [c][p]
    float* wu   = (float*)(ws + 2048 + 3 * 16384);     // 16 KB  [d][p]
    float* pd   = (float*)(ws + 2048 + 4 * 16384);     // 576 KB [p][n]
    float* lw   = (float*)(ws + 2048 + 4 * 16384 + 589824);  // 9.4 MB [b][p][n]
    // total ws usage: ~10.1 MB

    float* out = (float*)d_out;

    k_kv<<<16, 256, 0, stream>>>(proto, kw, kb, vw, vb, wk, wv, sums);
    k_mu<<<32, 256, 0, stream>>>(wk, wv, qw, qb, ow, wm, wu, s0);
    k_pd<<<36, 256, 0, stream>>>(pos, wm, pd);
    k_logits<<<2304, 64, 0, stream>>>(x, wm, s0, pd, lw);
    k_out<<<dim3(9, 32, 16), 256, 0, stream>>>(lw, wu, ob, out);
    k_local<<<dim3(256, 16), 256, 0, stream>>>(x, dww, bng, bnb, bnm, bnv, out, sums);
    k_norm<<<36864, 256, 0, stream>>>(sums, gng, gnb, out);
}